// Round 1
// baseline (163.761 us; speedup 1.0000x reference)
//
#include <hip/hip_runtime.h>
#include <hip/hip_bf16.h>

#define NB   64
#define SL   1024
#define EMB  128
#define NSK  1000
#define TJ   64
#define TI   64
#define SB   136   // LDS row stride in bf16 elems: 272B = 17*16B -> aligned b128, balanced banks

using short8  = __attribute__((ext_vector_type(8))) short;
using floatx4 = __attribute__((ext_vector_type(4))) float;

__device__ inline unsigned cvt2(float x, float y) {
    float2 f; f.x = x; f.y = y;
    __hip_bfloat162 h = __float22bfloat162_rn(f);
    unsigned u; __builtin_memcpy(&u, &h, sizeof(u));
    return u;   // low 16 = x, high 16 = y
}

// exact fp32 recompute for duplicate-timestamp pairs (dt==0, i<j):
// contribution = alpha_dot * exp(beta' * 14.306765580733931)   [= -log(1e-10)/log(5)]
__device__ __noinline__ float fixup_pair(const float* __restrict__ air,
                                         const float* __restrict__ bir,
                                         const float* __restrict__ asr,
                                         const float* __restrict__ bsr) {
    float da = 0.f, db = 0.f;
    for (int k = 0; k < EMB; ++k) {
        da += air[k] * asr[k];
        db += bir[k] * bsr[k];
    }
    float beta = fminf(fmaxf(db + 1.f, 0.f), 10.f);
    return da * __expf(beta * 14.30676558073393f);
}

extern "C" __global__ __launch_bounds__(256)
void hawkes_main(const int*   __restrict__ inp,     // (B,4,L) int32: skills,problems,labels,times
                 const float* __restrict__ pbase,   // (20000,1)
                 const float* __restrict__ sbase,   // (1000,1)
                 const float* __restrict__ ainter,  // (2000,128)
                 const float* __restrict__ askill,  // (1000,128)
                 const float* __restrict__ bint,    // (2000,128)
                 const float* __restrict__ bsk,     // (1000,128)
                 float*       __restrict__ out)     // (B,L)
{
    __shared__ unsigned short lA[2][TI][SB];   // [0]=alpha_inter rows, [1]=beta_inter rows (bf16)

    const int bid  = blockIdx.x;
    const int b    = bid & (NB - 1);
    const int jt   = (SL / TJ - 1) - (bid >> 6);   // big tiles first
    const int tid  = threadIdx.x;
    const int w    = tid >> 6;        // wave 0..3 -> j strip
    const int l    = tid & 63;
    const int quad = l >> 4;          // 0..3
    const int col  = l & 15;          // 0..15

    const int* __restrict__ binp = inp + b * 4 * SL;

    const int jlane = jt * TJ + w * 16 + col;
    const int sk_j  = binp[jlane];
    const int tj    = binp[3 * SL + jlane];
    const float* asr = askill + (long)sk_j * EMB;
    const float* bsr = bsk    + (long)sk_j * EMB;

    // ---- preload B fragments (fixed for whole block) into registers ----
    short8 bfa[4], bfb[4];
#pragma unroll
    for (int ks = 0; ks < 4; ++ks) {
        int k0 = ks * 32 + quad * 8;
        float4 fa0 = *(const float4*)(asr + k0);
        float4 fa1 = *(const float4*)(asr + k0 + 4);
        float4 fb0 = *(const float4*)(bsr + k0);
        float4 fb1 = *(const float4*)(bsr + k0 + 4);
        union { unsigned u[4]; short8 s; } ua, ub;
        ua.u[0] = cvt2(fa0.x, fa0.y); ua.u[1] = cvt2(fa0.z, fa0.w);
        ua.u[2] = cvt2(fa1.x, fa1.y); ua.u[3] = cvt2(fa1.z, fa1.w);
        ub.u[0] = cvt2(fb0.x, fb0.y); ub.u[1] = cvt2(fb0.z, fb0.w);
        ub.u[2] = cvt2(fb1.x, fb1.y); ub.u[3] = cvt2(fb1.z, fb1.w);
        bfa[ks] = ua.s; bfb[ks] = ub.s;
    }

    float sum = 0.f;

    // staging role: thread -> (row, quarter of the 128-dim embedding)
    const int srow = tid >> 2;
    const int sq   = tid & 3;

    for (int it = 0; it <= jt; ++it) {
        const int itb = it * TI;

        // ---- stage A tiles (gather + fp32->bf16) ----
        {
            const int irow  = itb + srow;
            const int ski   = binp[irow];
            const int li    = binp[2 * SL + irow];
            const long intr = ski + (long)li * NSK;
            const float* sA = ainter + intr * EMB + sq * 32;
            const float* sBm = bint  + intr * EMB + sq * 32;
            unsigned short* dA = &lA[0][srow][sq * 32];
            unsigned short* dB = &lA[1][srow][sq * 32];
#pragma unroll
            for (int c = 0; c < 4; ++c) {
                float4 f0 = *(const float4*)(sA + c * 8);
                float4 f1 = *(const float4*)(sA + c * 8 + 4);
                uint4 pk;
                pk.x = cvt2(f0.x, f0.y); pk.y = cvt2(f0.z, f0.w);
                pk.z = cvt2(f1.x, f1.y); pk.w = cvt2(f1.z, f1.w);
                *(uint4*)(dA + c * 8) = pk;
                float4 g0 = *(const float4*)(sBm + c * 8);
                float4 g1 = *(const float4*)(sBm + c * 8 + 4);
                uint4 qk;
                qk.x = cvt2(g0.x, g0.y); qk.y = cvt2(g0.z, g0.w);
                qk.z = cvt2(g1.x, g1.y); qk.w = cvt2(g1.z, g1.w);
                *(uint4*)(dB + c * 8) = qk;
            }
        }
        __syncthreads();

        // ---- compute: 4 sub-tiles of 16 i's ----
#pragma unroll
        for (int isub = 0; isub < 4; ++isub) {
            floatx4 acca = {0.f, 0.f, 0.f, 0.f};
            floatx4 accb = {0.f, 0.f, 0.f, 0.f};
#pragma unroll
            for (int ks = 0; ks < 4; ++ks) {
                int k0 = ks * 32 + quad * 8;
                short8 av = *(const short8*)&lA[0][isub * 16 + col][k0];
                short8 bv = *(const short8*)&lA[1][isub * 16 + col][k0];
                acca = __builtin_amdgcn_mfma_f32_16x16x32_bf16(av, bfa[ks], acca, 0, 0, 0);
                accb = __builtin_amdgcn_mfma_f32_16x16x32_bf16(bv, bfb[ks], accb, 0, 0, 0);
            }
            const int ibase = itb + isub * 16 + quad * 4;   // C row = quad*4+reg
            const int4 t4 = *(const int4*)(binp + 3 * SL + ibase);
#pragma unroll
            for (int r = 0; r < 4; ++r) {
                const int iidx = ibase + r;
                if (iidx < jlane) {
                    const int ti = (r == 0) ? t4.x : (r == 1) ? t4.y : (r == 2) ? t4.z : t4.w;
                    const int dt = tj - ti;   // >= 0 (times sorted, i<j)
                    if (dt != 0) {
                        float beta = fminf(fmaxf(accb[r] + 1.f, 0.f), 10.f);
                        float lc   = __log2f((float)dt) * 0.43067655807339306f; // log5(dt) in log2 units
                        sum += acca[r] * exp2f(-beta * lc);
                    } else {
                        // rare duplicate-timestamp pair: exact fp32 path
                        const int ski   = binp[iidx];
                        const int li    = binp[2 * SL + iidx];
                        const long intr = ski + (long)li * NSK;
                        sum += fixup_pair(ainter + intr * EMB, bint + intr * EMB, asr, bsr);
                    }
                }
            }
        }
        __syncthreads();
    }

    // reduce the 4 quads holding the same j
    sum += __shfl_xor(sum, 16, 64);
    sum += __shfl_xor(sum, 32, 64);

    if (quad == 0) {
        const float bias = pbase[binp[SL + jlane]] + sbase[sk_j];
        const float x = bias + sum;
        out[(long)b * SL + jlane] = 1.f / (1.f + __expf(-x));
    }
}

extern "C" void kernel_launch(void* const* d_in, const int* in_sizes, int n_in,
                              void* d_out, int out_size, void* d_ws, size_t ws_size,
                              hipStream_t stream) {
    const int*   inp = (const int*)d_in[0];
    const float* pb  = (const float*)d_in[1];
    const float* sb  = (const float*)d_in[2];
    const float* ai  = (const float*)d_in[3];
    const float* as  = (const float*)d_in[4];
    const float* bi  = (const float*)d_in[5];
    const float* bs  = (const float*)d_in[6];
    hawkes_main<<<dim3(NB * (SL / TJ)), dim3(256), 0, stream>>>(
        inp, pb, sb, ai, as, bi, bs, (float*)d_out);
}

// Round 2
// 131.642 us; speedup vs baseline: 1.2440x; 1.2440x over previous
//
#include <hip/hip_runtime.h>
#include <hip/hip_bf16.h>

#define NB   64
#define SL   1024
#define EMB  128
#define NSK  1000
#define TJ   64
#define TI   64
#define SB   136   // LDS row stride in bf16 elems: 272B = 17*16B -> aligned b128, balanced banks
#define NS   4     // split-K factor over i-tiles

// bf16 table layout in ws (elements):
#define AI_OFF 0
#define BI_OFF 256000
#define AS_OFF 512000
#define BS_OFF 640000
#define TB_ELEMS 768000
#define ACC_BYTE_OFF (TB_ELEMS * 2)            // 1,536,000 B, 16B-aligned
#define ACC_ELEMS (NS * NB * SL)               // 262144 floats

using short8  = __attribute__((ext_vector_type(8))) short;
using floatx4 = __attribute__((ext_vector_type(4))) float;

__device__ inline unsigned cvt2(float x, float y) {
    float2 f; f.x = x; f.y = y;
    __hip_bfloat162 h = __float22bfloat162_rn(f);
    unsigned u; __builtin_memcpy(&u, &h, sizeof(u));
    return u;   // low 16 = x, high 16 = y
}

// ---- one-time fp32 -> bf16 table conversion (8 elems/thread) ----
extern "C" __global__ __launch_bounds__(256)
void cvt_tables(const float* __restrict__ ai, const float* __restrict__ bi,
                const float* __restrict__ as, const float* __restrict__ bs,
                unsigned short* __restrict__ dst)
{
    const int t = blockIdx.x * 256 + threadIdx.x;   // 96000 threads
    const long e = (long)t * 8;
    const float* src;
    if      (e < 256000) src = ai + e;
    else if (e < 512000) src = bi + (e - 256000);
    else if (e < 640000) src = as + (e - 512000);
    else                 src = bs + (e - 640000);
    float4 f0 = *(const float4*)src;
    float4 f1 = *(const float4*)(src + 4);
    uint4 pk;
    pk.x = cvt2(f0.x, f0.y); pk.y = cvt2(f0.z, f0.w);
    pk.z = cvt2(f1.x, f1.y); pk.w = cvt2(f1.z, f1.w);
    *(uint4*)(dst + e) = pk;
}

// exact fp32 recompute for duplicate-timestamp pairs (dt==0, i<j):
// contribution = alpha_dot * exp(beta' * 14.306765580733931)   [= -log(1e-10)/log(5)]
__device__ __noinline__ float fixup_pair(const float* __restrict__ air,
                                         const float* __restrict__ bir,
                                         const float* __restrict__ asr,
                                         const float* __restrict__ bsr) {
    float da = 0.f, db = 0.f;
    for (int k = 0; k < EMB; ++k) {
        da += air[k] * asr[k];
        db += bir[k] * bsr[k];
    }
    float beta = fminf(fmaxf(db + 1.f, 0.f), 10.f);
    return da * __expf(beta * 14.30676558073393f);
}

extern "C" __global__ __launch_bounds__(256)
void hawkes_main(const int*   __restrict__ inp,     // (B,4,L) int32
                 const float* __restrict__ ainter,  // fp32, fixup only
                 const float* __restrict__ askill,  // fp32, fixup only
                 const float* __restrict__ bint,    // fp32, fixup only
                 const float* __restrict__ bsk,     // fp32, fixup only
                 const unsigned short* __restrict__ tb,  // bf16 tables
                 float*       __restrict__ acc)     // (NS,B,L) partial sums
{
    __shared__ unsigned short lA[2][TI][SB];   // [0]=alpha_inter rows, [1]=beta_inter rows (bf16)

    const int bid  = blockIdx.x;
    const int b    = bid & (NB - 1);
    const int r    = bid >> 6;                 // 0..63
    const int jt   = (SL / TJ - 1) - ((r >> 2) & 15);   // big tiles first
    const int s    = r & 3;                    // split id, interleaved for balance
    const int tid  = threadIdx.x;
    const int w    = tid >> 6;        // wave 0..3 -> j strip
    const int l    = tid & 63;
    const int quad = l >> 4;          // 0..3
    const int col  = l & 15;          // 0..15

    const int* __restrict__ binp = inp + b * 4 * SL;

    const int jlane = jt * TJ + w * 16 + col;
    const int sk_j  = binp[jlane];
    const int tj    = binp[3 * SL + jlane];
    const float* asr = askill + (long)sk_j * EMB;   // fp32, fixup path
    const float* bsr = bsk    + (long)sk_j * EMB;

    // ---- preload B fragments (bf16 tables, no cvt) ----
    const unsigned short* asr16 = tb + AS_OFF + (long)sk_j * EMB;
    const unsigned short* bsr16 = tb + BS_OFF + (long)sk_j * EMB;
    short8 bfa[4], bfb[4];
#pragma unroll
    for (int ks = 0; ks < 4; ++ks) {
        int k0 = ks * 32 + quad * 8;
        bfa[ks] = *(const short8*)(asr16 + k0);
        bfb[ks] = *(const short8*)(bsr16 + k0);
    }

    float sum = 0.f;

    // staging role: thread -> (row, quarter of the 128-dim embedding)
    const int srow = tid >> 2;
    const int sq   = tid & 3;

    for (int it = s; it <= jt; it += NS) {
        const int itb = it * TI;

        // ---- stage A tiles: pure bf16 copy, no conversion ----
        {
            const int irow  = itb + srow;
            const int ski   = binp[irow];
            const int li    = binp[2 * SL + irow];
            const long intr = ski + (long)li * NSK;
            const unsigned short* sA = tb + AI_OFF + intr * EMB + sq * 32;
            const unsigned short* sBm = tb + BI_OFF + intr * EMB + sq * 32;
            uint4 a0 = *(const uint4*)(sA);
            uint4 a1 = *(const uint4*)(sA + 8);
            uint4 a2 = *(const uint4*)(sA + 16);
            uint4 a3 = *(const uint4*)(sA + 24);
            uint4 b0 = *(const uint4*)(sBm);
            uint4 b1 = *(const uint4*)(sBm + 8);
            uint4 b2 = *(const uint4*)(sBm + 16);
            uint4 b3 = *(const uint4*)(sBm + 24);
            unsigned short* dA = &lA[0][srow][sq * 32];
            unsigned short* dB = &lA[1][srow][sq * 32];
            *(uint4*)(dA)      = a0;
            *(uint4*)(dA + 8)  = a1;
            *(uint4*)(dA + 16) = a2;
            *(uint4*)(dA + 24) = a3;
            *(uint4*)(dB)      = b0;
            *(uint4*)(dB + 8)  = b1;
            *(uint4*)(dB + 16) = b2;
            *(uint4*)(dB + 24) = b3;
        }
        __syncthreads();

        // ---- compute: 4 sub-tiles of 16 i's ----
#pragma unroll
        for (int isub = 0; isub < 4; ++isub) {
            floatx4 acca = {0.f, 0.f, 0.f, 0.f};
            floatx4 accb = {0.f, 0.f, 0.f, 0.f};
#pragma unroll
            for (int ks = 0; ks < 4; ++ks) {
                int k0 = ks * 32 + quad * 8;
                short8 av = *(const short8*)&lA[0][isub * 16 + col][k0];
                short8 bv = *(const short8*)&lA[1][isub * 16 + col][k0];
                acca = __builtin_amdgcn_mfma_f32_16x16x32_bf16(av, bfa[ks], acca, 0, 0, 0);
                accb = __builtin_amdgcn_mfma_f32_16x16x32_bf16(bv, bfb[ks], accb, 0, 0, 0);
            }
            const int ibase = itb + isub * 16 + quad * 4;   // C row = quad*4+reg
            const int4 t4 = *(const int4*)(binp + 3 * SL + ibase);
#pragma unroll
            for (int rr = 0; rr < 4; ++rr) {
                const int iidx = ibase + rr;
                if (iidx < jlane) {
                    const int ti = (rr == 0) ? t4.x : (rr == 1) ? t4.y : (rr == 2) ? t4.z : t4.w;
                    const int dt = tj - ti;   // >= 0 (times sorted, i<j)
                    if (dt != 0) {
                        float beta = fminf(fmaxf(accb[rr] + 1.f, 0.f), 10.f);
                        float lc   = __log2f((float)dt) * 0.43067655807339306f; // log5 in log2 units
                        sum += acca[rr] * exp2f(-beta * lc);
                    } else {
                        // rare duplicate-timestamp pair: exact fp32 path
                        const int ski   = binp[iidx];
                        const int li    = binp[2 * SL + iidx];
                        const long intr = ski + (long)li * NSK;
                        sum += fixup_pair(ainter + intr * EMB, bint + intr * EMB, asr, bsr);
                    }
                }
            }
        }
        __syncthreads();
    }

    // reduce the 4 quads holding the same j
    sum += __shfl_xor(sum, 16, 64);
    sum += __shfl_xor(sum, 32, 64);

    if (quad == 0) {
        acc[(((long)s * NB + b) << 10) + jlane] = sum;
    }
}

extern "C" __global__ __launch_bounds__(256)
void hawkes_finalize(const int* __restrict__ inp, const float* __restrict__ pbase,
                     const float* __restrict__ sbase, const float* __restrict__ acc,
                     float* __restrict__ out)
{
    const int t = blockIdx.x * 256 + threadIdx.x;   // 65536
    const int b = t >> 10, j = t & (SL - 1);
    const int* binp = inp + b * 4 * SL;
    float sum = acc[t] + acc[NB * SL + t] + acc[2 * NB * SL + t] + acc[3 * NB * SL + t];
    const float x = pbase[binp[SL + j]] + sbase[binp[j]] + sum;
    out[t] = 1.f / (1.f + __expf(-x));
}

extern "C" void kernel_launch(void* const* d_in, const int* in_sizes, int n_in,
                              void* d_out, int out_size, void* d_ws, size_t ws_size,
                              hipStream_t stream) {
    const int*   inp = (const int*)d_in[0];
    const float* pb  = (const float*)d_in[1];
    const float* sb  = (const float*)d_in[2];
    const float* ai  = (const float*)d_in[3];
    const float* as  = (const float*)d_in[4];
    const float* bi  = (const float*)d_in[5];
    const float* bs  = (const float*)d_in[6];

    unsigned short* tb  = (unsigned short*)d_ws;
    float*          acc = (float*)((char*)d_ws + ACC_BYTE_OFF);

    cvt_tables<<<dim3(96000 / 256), dim3(256), 0, stream>>>(ai, bi, as, bs, tb);
    hawkes_main<<<dim3(NB * (SL / TJ) * NS), dim3(256), 0, stream>>>(
        inp, ai, as, bi, bs, tb, acc);
    hawkes_finalize<<<dim3(NB * SL / 256), dim3(256), 0, stream>>>(
        inp, pb, sb, acc, (float*)d_out);
}